// Round 2
// baseline (232.027 us; speedup 1.0000x reference)
//
#include <hip/hip_runtime.h>
#include <math.h>

// B=32, C=3, H=W=512. Reference = mean_b( min_{c,h,w} input[b] ):
// reflect-pad only duplicates interior values, so min over padded == min
// over original; min over C then H then W == global min per batch.
//
// Fused single-dispatch reduction:
//   2048 blocks (64 per batch) x 256 threads, 12 float4/thread nontemporal
//   streaming reads -> block min -> partial[2048] in d_ws.
//   Last block (device-scope atomic counter) folds partials: per-batch min
//   over 64 partials, then mean over 32 batches -> d_out[0].

#define VEC4_PER_BATCH  196608          // 3*512*512/4
#define BLOCKS_PER_BATCH 64
#define VEC4_PER_BLOCK  (VEC4_PER_BATCH / BLOCKS_PER_BATCH)   // 3072
#define THREADS 256
#define VEC4_PER_THREAD (VEC4_PER_BLOCK / THREADS)            // 12
#define NBLOCKS (BLOCKS_PER_BATCH * 32)                       // 2048

typedef float f4 __attribute__((ext_vector_type(4)));

__global__ __launch_bounds__(THREADS) void dcp_fused(
        const float* __restrict__ in, float* __restrict__ out,
        unsigned int* __restrict__ counter, float* __restrict__ partial) {
    const int b  = blockIdx.y;
    const int bx = blockIdx.x;
    const int t  = threadIdx.x;

    const f4* base = reinterpret_cast<const f4*>(in) +
                     (size_t)b * VEC4_PER_BATCH + (size_t)bx * VEC4_PER_BLOCK;

    float m = INFINITY;
#pragma unroll
    for (int i = 0; i < VEC4_PER_THREAD; ++i) {
        f4 v = __builtin_nontemporal_load(base + i * THREADS + t);
        m = fminf(m, fminf(fminf(v.x, v.y), fminf(v.z, v.w)));
    }

    // wave-64 shuffle reduce (min)
#pragma unroll
    for (int off = 32; off > 0; off >>= 1)
        m = fminf(m, __shfl_down(m, off, 64));

    __shared__ float smem[THREADS / 64];
    __shared__ bool last;
    if ((t & 63) == 0) smem[t >> 6] = m;
    __syncthreads();
    if (t == 0) {
        float r = fminf(fminf(smem[0], smem[1]), fminf(smem[2], smem[3]));
        partial[b * BLOCKS_PER_BATCH + bx] = r;
        __threadfence();                                   // release partial
        unsigned int prev = atomicAdd(counter, 1u);        // device scope
        last = (prev == NBLOCKS - 1);
    }
    __syncthreads();
    if (!last) return;

    // ---- final block: fold 2048 partials -> mean of per-batch mins ----
    __threadfence();                                       // acquire partials
    const int batch = t >> 3;         // 0..31
    const int sub   = t & 7;          // 0..7
    float r = INFINITY;
#pragma unroll
    for (int i = 0; i < 8; ++i)
        r = fminf(r, partial[batch * BLOCKS_PER_BATCH + sub * 8 + i]);
    // reduce within each 8-lane group (groups never cross the wave boundary)
#pragma unroll
    for (int off = 1; off < 8; off <<= 1)
        r = fminf(r, __shfl_xor(r, off, 64));

    __shared__ float bmin[32];
    if (sub == 0) bmin[batch] = r;
    __syncthreads();
    if (t < 64) {
        float v = (t < 32) ? bmin[t] : 0.0f;
#pragma unroll
        for (int off = 32; off > 0; off >>= 1)
            v += __shfl_down(v, off, 64);
        if (t == 0) out[0] = v * (1.0f / 32.0f);
    }
}

extern "C" void kernel_launch(void* const* d_in, const int* in_sizes, int n_in,
                              void* d_out, int out_size, void* d_ws, size_t ws_size,
                              hipStream_t stream) {
    const float* in = (const float*)d_in[0];
    float* out = (float*)d_out;
    unsigned int* counter = (unsigned int*)d_ws;           // 4 B @ offset 0
    float* partial = (float*)((char*)d_ws + 256);          // 2048 floats

    hipMemsetAsync(counter, 0, sizeof(unsigned int), stream);  // graph memset node
    dim3 grid(BLOCKS_PER_BATCH, 32);
    dcp_fused<<<grid, THREADS, 0, stream>>>(in, out, counter, partial);
}

// Round 3
// 149.529 us; speedup vs baseline: 1.5517x; 1.5517x over previous
//
#include <hip/hip_runtime.h>
#include <math.h>

// B=32, C=3, H=W=512. Reference = mean_b( min_{c,h,w} input[b] ):
// reflect-pad only duplicates interior values, so min over padded == min
// over original; chained C/H/W mins == global min per batch image.
//
// Single dispatch, NO device fences (round-2's per-block __threadfence
// serialized 2048 blocks at ~50ns each => 118us kernel; removed):
//   2048 blocks (64/batch) x 256 threads, float4 coalesced stream ->
//   block min -> device-scope atomicMin on monotone uint key per batch.
//   Ordering min-before-counter via returning atomic + vmcnt wait (cheap,
//   no L2 flush). Last block reads slots with coherent no-op atomics,
//   unmaps, means over 32 batches -> d_out[0].

#define VEC4_PER_BATCH  196608          // 3*512*512/4
#define BLOCKS_PER_BATCH 64
#define VEC4_PER_BLOCK  (VEC4_PER_BATCH / BLOCKS_PER_BATCH)   // 3072
#define THREADS 256
#define VEC4_PER_THREAD (VEC4_PER_BLOCK / THREADS)            // 12
#define NBLOCKS (BLOCKS_PER_BATCH * 32)                       // 2048

typedef float f4 __attribute__((ext_vector_type(4)));

// Monotone float->uint map: uint order == float order (no NaN in inputs).
__device__ __forceinline__ unsigned fkey(float f) {
    unsigned u = __float_as_uint(f);
    return (u & 0x80000000u) ? ~u : (u | 0x80000000u);
}
__device__ __forceinline__ float funkey(unsigned k) {
    return __uint_as_float((k & 0x80000000u) ? (k ^ 0x80000000u) : ~k);
}

__global__ __launch_bounds__(THREADS) void dcp_fused2(
        const float* __restrict__ in, float* __restrict__ out,
        unsigned* __restrict__ counter, unsigned* __restrict__ slots) {
    const int b  = blockIdx.y;
    const int bx = blockIdx.x;
    const int t  = threadIdx.x;

    const f4* base = reinterpret_cast<const f4*>(in) +
                     (size_t)b * VEC4_PER_BATCH + (size_t)bx * VEC4_PER_BLOCK;

    float m = INFINITY;
#pragma unroll
    for (int i = 0; i < VEC4_PER_THREAD; ++i) {
        f4 v = base[i * THREADS + t];
        m = fminf(m, fminf(fminf(v.x, v.y), fminf(v.z, v.w)));
    }

    // wave-64 shuffle reduce (min)
#pragma unroll
    for (int off = 32; off > 0; off >>= 1)
        m = fminf(m, __shfl_down(m, off, 64));

    __shared__ float smem[THREADS / 64];
    __shared__ bool last;
    if ((t & 63) == 0) smem[t >> 6] = m;
    __syncthreads();
    if (t == 0) {
        float r = fminf(fminf(smem[0], smem[1]), fminf(smem[2], smem[3]));
        // Device-scope atomic publish; returning form so we can prove
        // completion (== global visibility at coherence point) before
        // touching the counter. No fence, no L2 writeback.
        unsigned old = atomicMin(&slots[b], fkey(r));
        asm volatile("" : "+v"(old) :: "memory");   // opaque: forces vmcnt wait on old
        if (old == 0x7F7F7F7Fu) slots[34] = old;    // never in practice; harmless ws scratch
        unsigned prev = atomicAdd(counter, 1u);
        last = (prev == NBLOCKS - 1);
    }
    __syncthreads();
    if (!last) return;

    // ---- final block: coherent-read 32 per-batch mins, mean -> out ----
    if (t < 64) {
        float v = 0.0f;
        if (t < 32) {
            unsigned k = atomicMin(&slots[t], 0xFFFFFFFFu);  // no-op, returns current
            v = funkey(k);
        }
#pragma unroll
        for (int off = 32; off > 0; off >>= 1)
            v += __shfl_down(v, off, 64);
        if (t == 0) out[0] = v * (1.0f / 32.0f);
    }
}

extern "C" void kernel_launch(void* const* d_in, const int* in_sizes, int n_in,
                              void* d_out, int out_size, void* d_ws, size_t ws_size,
                              hipStream_t stream) {
    const float* in = (const float*)d_in[0];
    float* out = (float*)d_out;
    unsigned* counter = (unsigned*)d_ws;                   // 4 B @ offset 0
    unsigned* slots   = (unsigned*)((char*)d_ws + 256);    // 32 keys (+scratch)

    hipMemsetAsync(counter, 0, sizeof(unsigned), stream);          // counter = 0
    hipMemsetAsync(slots, 0xFF, 40 * sizeof(unsigned), stream);    // keys = UINT_MAX
    dim3 grid(BLOCKS_PER_BATCH, 32);
    dcp_fused2<<<grid, THREADS, 0, stream>>>(in, out, counter, slots);
}

// Round 4
// 134.559 us; speedup vs baseline: 1.7243x; 1.1112x over previous
//
#include <hip/hip_runtime.h>
#include <math.h>

// B=32, C=3, H=W=512. Reference = mean_b( min_{c,h,w} input[b] ):
// reflect-pad only duplicates interior values, so min over padded == min
// over original; chained C/H/W mins == global min per batch image.
//
// Two-kernel structure (best measured: R1 = 146.0 us total; R3 fused+memsets
// = 149.5 us — fusion's atomic tail + extra nodes cost more than the saved
// launch gap). This round: R1 structure + nontemporal streaming loads
// (input is read exactly once; skip L2/LLC allocation).
//
// Stage 1: 2048 blocks (64/batch) x 256 threads, 12 float4/thread nt loads
//          -> block min -> partial[2048] in d_ws.
// Stage 2: one 64-thread block: per-batch min over 64 partials, mean -> out.

#define VEC4_PER_BATCH  196608          // 3*512*512/4
#define BLOCKS_PER_BATCH 64
#define VEC4_PER_BLOCK  (VEC4_PER_BATCH / BLOCKS_PER_BATCH)   // 3072
#define THREADS 256
#define VEC4_PER_THREAD (VEC4_PER_BLOCK / THREADS)            // 12

typedef float f4 __attribute__((ext_vector_type(4)));

__global__ __launch_bounds__(THREADS) void dcp_batch_min_partial(
        const float* __restrict__ in, float* __restrict__ partial) {
    const int blk = blockIdx.x;           // 0..2047
    const int b   = blk >> 6;             // batch 0..31
    const int bx  = blk & 63;             // sub-block within batch
    const int t   = threadIdx.x;

    const f4* base = reinterpret_cast<const f4*>(in) +
                     (size_t)b * VEC4_PER_BATCH + (size_t)bx * VEC4_PER_BLOCK;

    float m = INFINITY;
#pragma unroll
    for (int i = 0; i < VEC4_PER_THREAD; ++i) {
        f4 v = __builtin_nontemporal_load(base + i * THREADS + t);
        m = fminf(m, fminf(fminf(v.x, v.y), fminf(v.z, v.w)));
    }

    // wave-64 shuffle reduce (min)
#pragma unroll
    for (int off = 32; off > 0; off >>= 1)
        m = fminf(m, __shfl_down(m, off, 64));

    __shared__ float smem[THREADS / 64];
    if ((t & 63) == 0) smem[t >> 6] = m;
    __syncthreads();
    if (t == 0) {
        float r = fminf(fminf(smem[0], smem[1]), fminf(smem[2], smem[3]));
        partial[blk] = r;
    }
}

__global__ __launch_bounds__(64) void dcp_finalize(
        const float* __restrict__ partial, float* __restrict__ out) {
    const int t = threadIdx.x;            // 64 threads, one wave
    const int batch = t >> 1;             // 0..31
    const int half  = t & 1;              // 0..1
    float r = INFINITY;
#pragma unroll
    for (int i = 0; i < 32; ++i)
        r = fminf(r, partial[batch * BLOCKS_PER_BATCH + half * 32 + i]);
    r = fminf(r, __shfl_xor(r, 1, 64));   // fold the two halves -> batch min
    // lanes with half==0 hold batch mins; sum them / 32
    float v = (half == 0) ? r : 0.0f;
#pragma unroll
    for (int off = 32; off > 0; off >>= 1)
        v += __shfl_down(v, off, 64);
    if (t == 0) out[0] = v * (1.0f / 32.0f);
}

extern "C" void kernel_launch(void* const* d_in, const int* in_sizes, int n_in,
                              void* d_out, int out_size, void* d_ws, size_t ws_size,
                              hipStream_t stream) {
    const float* in = (const float*)d_in[0];
    float* out = (float*)d_out;
    float* partial = (float*)d_ws;        // 2048 floats = 8 KB

    dcp_batch_min_partial<<<2048, THREADS, 0, stream>>>(in, partial);
    dcp_finalize<<<1, 64, 0, stream>>>(partial, out);
}